// Round 1
// baseline (451.227 us; speedup 1.0000x reference)
//
#include <hip/hip_runtime.h>

#define N_NODES 50000
#define N_EDGES 1000000
// xr layout: [node][9][64]; relation 8 == self-loop transform.

// ---- ws layout (bytes, 256-aligned) ----
#define A_DEGIN   0          // int[50000]
#define A_DEGOUT  200192     // int[50000]
#define A_CURSOR  400384     // int[50000]
#define A_ROWPTR  600576     // int[50001]
#define A_CSRROW  800768     // int[1e6]
#define A_CSRSRC  4800768    // int[1e6]
#define A_WALL    8800768    // float[9*64*64]
#define A_HS      8948224    // float[50000*64]
#define A_XR      21748224   // float[50000*576]  (ends at 136,948,224)

// K0: Wall[r][i][o] = sum_b comp[r][b]*basis[b][i][o]; Wall[8] = loop_weight
__global__ void k_wall(const float* __restrict__ comp, const float* __restrict__ basis,
                       const float* __restrict__ loopw, float* __restrict__ Wall) {
    int idx = blockIdx.x * 256 + threadIdx.x;
    if (idx >= 9 * 4096) return;
    int r = idx >> 12, io = idx & 4095;
    float acc;
    if (r < 8) {
        acc = 0.f;
        #pragma unroll
        for (int b = 0; b < 30; ++b) acc += comp[r * 30 + b] * basis[b * 4096 + io];
    } else {
        acc = loopw[io];
    }
    Wall[idx] = acc;
}

// K1: degree histograms
__global__ void k_hist(const int* __restrict__ ei, int* deg_in, int* deg_out) {
    int e = blockIdx.x * 256 + threadIdx.x;
    if (e >= N_EDGES) return;
    atomicAdd(&deg_out[ei[e]], 1);
    atomicAdd(&deg_in[ei[N_EDGES + e]], 1);
}

// K2: exclusive scan of deg_in -> rowptr (single block, 1024 threads)
__global__ void k_scan(const int* __restrict__ deg, int* __restrict__ rowptr) {
    __shared__ int wsum[16];
    __shared__ int btot;
    int tid = threadIdx.x, lane = tid & 63, wid = tid >> 6;
    int running = 0;
    for (int base = 0; base < N_NODES; base += 1024) {
        int i = base + tid;
        int v = (i < N_NODES) ? deg[i] : 0;
        int x = v;
        #pragma unroll
        for (int d = 1; d < 64; d <<= 1) {
            int y = __shfl_up(x, d);
            if (lane >= d) x += y;
        }
        if (lane == 63) wsum[wid] = x;
        __syncthreads();
        if (tid == 0) {
            int s = 0;
            #pragma unroll
            for (int w = 0; w < 16; ++w) { int t = wsum[w]; wsum[w] = s; s += t; }
            btot = s;
        }
        __syncthreads();
        int excl = running + wsum[wid] + (x - v);
        if (i < N_NODES) rowptr[i] = excl;
        running += btot;
        __syncthreads();
    }
    if (tid == 0) rowptr[N_NODES] = N_EDGES;
}

// K3: scatter edges into CSR-by-dst slots
__global__ void k_fill(const int* __restrict__ ei, const int* __restrict__ etype,
                       const int* __restrict__ rowptr, int* cursor,
                       int* __restrict__ csr_row, int* __restrict__ csr_src) {
    int e = blockIdx.x * 256 + threadIdx.x;
    if (e >= N_EDGES) return;
    int s = ei[e], d = ei[N_EDGES + e];
    int pos = rowptr[d] + atomicAdd(&cursor[d], 1);
    csr_row[pos] = s * 9 + etype[e];
    csr_src[pos] = s;
}

// K4: xr[n][r][64] = x[n][:] @ Wall[r]  (block: 64 nodes x 64 cols of one relation)
__global__ __launch_bounds__(256) void k_xr(const float* __restrict__ x,
                                            const float* __restrict__ Wall,
                                            float* __restrict__ xr) {
    __shared__ __align__(16) float At[64 * 68];  // [k][n], pad to 68
    __shared__ __align__(16) float Wt[64 * 64];  // [k][c]
    int t = threadIdx.x;
    int n0 = blockIdx.x * 64;
    int r = blockIdx.y;
    #pragma unroll
    for (int j = 0; j < 16; ++j) {
        int f = t + j * 256;
        int n = f >> 6, k = f & 63;
        float v = (n0 + n < N_NODES) ? x[(n0 + n) * 64 + k] : 0.f;
        At[k * 68 + n] = v;
    }
    #pragma unroll
    for (int j = 0; j < 16; ++j) {
        int f = t + j * 256;
        Wt[f] = Wall[r * 4096 + f];
    }
    __syncthreads();
    int cg = t & 15, rg = t >> 4;  // 4 cols @ 4*cg, 4 rows @ 4*rg
    float acc[4][4];
    #pragma unroll
    for (int i = 0; i < 4; ++i)
        #pragma unroll
        for (int j = 0; j < 4; ++j) acc[i][j] = 0.f;
    #pragma unroll 4
    for (int k = 0; k < 64; ++k) {
        float4 a = *(const float4*)&At[k * 68 + 4 * rg];
        float4 w = *(const float4*)&Wt[k * 64 + 4 * cg];
        acc[0][0] += a.x * w.x; acc[0][1] += a.x * w.y; acc[0][2] += a.x * w.z; acc[0][3] += a.x * w.w;
        acc[1][0] += a.y * w.x; acc[1][1] += a.y * w.y; acc[1][2] += a.y * w.z; acc[1][3] += a.y * w.w;
        acc[2][0] += a.z * w.x; acc[2][1] += a.z * w.y; acc[2][2] += a.z * w.z; acc[2][3] += a.z * w.w;
        acc[3][0] += a.w * w.x; acc[3][1] += a.w * w.y; acc[3][2] += a.w * w.z; acc[3][3] += a.w * w.w;
    }
    #pragma unroll
    for (int i = 0; i < 4; ++i) {
        int n = n0 + 4 * rg + i;
        if (n < N_NODES) {
            float4 o = make_float4(acc[i][0], acc[i][1], acc[i][2], acc[i][3]);
            *(float4*)&xr[n * 576 + r * 64 + 4 * cg] = o;
        }
    }
}

// K5: hs[v] = (sum_in-edges xr[src*9+et] + xr[v*9+8] + bias1) * rsqrt(deg_out[v])
__global__ __launch_bounds__(256) void k_agg1(const float* __restrict__ xr,
                                              const int* __restrict__ csr_row,
                                              const int* __restrict__ rowptr,
                                              const int* __restrict__ deg_out,
                                              const float* __restrict__ bias1,
                                              float* __restrict__ hs) {
    int wid = threadIdx.x >> 6, lane = threadIdx.x & 63;
    int v = blockIdx.x * 4 + wid;
    if (v >= N_NODES) return;
    float acc = xr[(v * 9 + 8) * 64 + lane] + bias1[lane];
    int j = rowptr[v], end = rowptr[v + 1];
    for (; j + 4 <= end; j += 4) {
        int r0 = csr_row[j], r1 = csr_row[j + 1], r2 = csr_row[j + 2], r3 = csr_row[j + 3];
        float a0 = xr[r0 * 64 + lane], a1 = xr[r1 * 64 + lane];
        float a2 = xr[r2 * 64 + lane], a3 = xr[r3 * 64 + lane];
        acc += a0; acc += a1; acc += a2; acc += a3;
    }
    for (; j < end; ++j) acc += xr[csr_row[j] * 64 + lane];
    float dg = (float)deg_out[v];
    if (dg < 1.f) dg = 1.f;
    hs[v * 64 + lane] = acc * rsqrtf(dg);
}

// K6: out[v] = (rsqrt(deg_in[v]) * sum_in-edges hs[src]) @ W2 + bias2
__global__ __launch_bounds__(256) void k_layer2(const float* __restrict__ hs,
                                                const int* __restrict__ csr_src,
                                                const int* __restrict__ rowptr,
                                                const int* __restrict__ deg_in,
                                                const float* __restrict__ w2,
                                                const float* __restrict__ bias2,
                                                float* __restrict__ out) {
    __shared__ __align__(16) float W2s[64 * 64];
    __shared__ __align__(16) float ys[4 * 64];
    int t = threadIdx.x;
    #pragma unroll
    for (int j = 0; j < 16; ++j) W2s[t + j * 256] = w2[t + j * 256];
    int wid = t >> 6, lane = t & 63;
    int v = blockIdx.x * 4 + wid;
    float acc = 0.f;
    int j = 0, end = 0;
    if (v < N_NODES) { j = rowptr[v]; end = rowptr[v + 1]; }
    for (; j + 4 <= end; j += 4) {
        int r0 = csr_src[j], r1 = csr_src[j + 1], r2 = csr_src[j + 2], r3 = csr_src[j + 3];
        float a0 = hs[r0 * 64 + lane], a1 = hs[r1 * 64 + lane];
        float a2 = hs[r2 * 64 + lane], a3 = hs[r3 * 64 + lane];
        acc += a0; acc += a1; acc += a2; acc += a3;
    }
    for (; j < end; ++j) acc += hs[csr_src[j] * 64 + lane];
    if (v < N_NODES) {
        float dg = (float)deg_in[v];
        if (dg < 1.f) dg = 1.f;
        ys[wid * 64 + lane] = acc * rsqrtf(dg);
    }
    __syncthreads();
    if (v >= N_NODES) return;
    float o = bias2[lane];
    const float* yrow = &ys[wid * 64];
    #pragma unroll 4
    for (int k = 0; k < 64; ++k) o += yrow[k] * W2s[k * 64 + lane];
    out[v * 64 + lane] = o;
}

extern "C" void kernel_launch(void* const* d_in, const int* in_sizes, int n_in,
                              void* d_out, int out_size, void* d_ws, size_t ws_size,
                              hipStream_t stream) {
    const float* x      = (const float*)d_in[0];
    const int*   ei     = (const int*)d_in[1];   // [2E]: src then dst
    // d_in[2] = edge_norm: unused by the reference
    const int*   etype  = (const int*)d_in[3];
    const float* basis  = (const float*)d_in[4];
    const float* comp   = (const float*)d_in[5];
    const float* loopw  = (const float*)d_in[6];
    const float* bias1  = (const float*)d_in[7];
    const float* w2     = (const float*)d_in[8];
    const float* bias2  = (const float*)d_in[9];
    float* out = (float*)d_out;

    char* ws = (char*)d_ws;
    int*   deg_in  = (int*)(ws + A_DEGIN);
    int*   deg_out = (int*)(ws + A_DEGOUT);
    int*   cursor  = (int*)(ws + A_CURSOR);
    int*   rowptr  = (int*)(ws + A_ROWPTR);
    int*   csr_row = (int*)(ws + A_CSRROW);
    int*   csr_src = (int*)(ws + A_CSRSRC);
    float* Wall    = (float*)(ws + A_WALL);
    float* hs      = (float*)(ws + A_HS);
    float* xr      = (float*)(ws + A_XR);

    // zero deg_in/deg_out/cursor (ws is poisoned 0xAA each call)
    hipMemsetAsync(ws, 0, 600576, stream);

    k_wall<<<144, 256, 0, stream>>>(comp, basis, loopw, Wall);
    k_hist<<<(N_EDGES + 255) / 256, 256, 0, stream>>>(ei, deg_in, deg_out);
    k_scan<<<1, 1024, 0, stream>>>(deg_in, rowptr);
    k_fill<<<(N_EDGES + 255) / 256, 256, 0, stream>>>(ei, etype, rowptr, cursor, csr_row, csr_src);
    k_xr<<<dim3((N_NODES + 63) / 64, 9), 256, 0, stream>>>(x, Wall, xr);
    k_agg1<<<N_NODES / 4, 256, 0, stream>>>(xr, csr_row, rowptr, deg_out, bias1, hs);
    k_layer2<<<N_NODES / 4, 256, 0, stream>>>(hs, csr_src, rowptr, deg_in, w2, bias2, out);
}

// Round 2
// 398.022 us; speedup vs baseline: 1.1337x; 1.1337x over previous
//
#include <hip/hip_runtime.h>

#define N_NODES 50000
#define N_EDGES 1000000
#define NB      128         // edge chunks
#define CHUNK   7813        // 128*7813 = 1,000,064 >= E
#define QN      12500       // nodes per LDS quarter (4*12500 = 50000)
#define NBLK2   196         // ceil(50000/256)

// ---- ws layout (bytes) ----
// part[NB][50000] uint (25.6 MB) lives at 0 and is DEAD after k_fill2;
// xr[50000][9][64] float (115.2 MB) reuses offset 0 after the build.
#define A_PART    0
#define A_XR      0
#define A_DEGP    115200000  // uint[50000] packed: deg_in<<16 | deg_out
#define A_ROWPTR  115400000  // int[50001]
#define A_BSUM    115600128  // int[196]
#define A_BBASE   115601024  // int[196]
#define A_CSR     115601920  // int2[1e6]: (src*9+etype, src)
#define A_HS      123601920  // float[50000*64]
#define A_WALL    136401920  // float[9*64*64]  (ends 136,549,376)

typedef unsigned int uint32;

// K0: Wall[r][i][o] = sum_b comp[r][b]*basis[b][i][o]; Wall[8] = loop_weight
__global__ void k_wall(const float* __restrict__ comp, const float* __restrict__ basis,
                       const float* __restrict__ loopw, float* __restrict__ Wall) {
    int idx = blockIdx.x * 256 + threadIdx.x;
    if (idx >= 9 * 4096) return;
    int r = idx >> 12, io = idx & 4095;
    float acc;
    if (r < 8) {
        acc = 0.f;
        #pragma unroll
        for (int b = 0; b < 30; ++b) acc += comp[r * 30 + b] * basis[b * 4096 + io];
    } else {
        acc = loopw[io];
    }
    Wall[idx] = acc;
}

// K1: per-chunk packed histograms via LDS atomics (no global atomics).
// part[b][v] = (in_count<<16) | out_count for chunk b.
__global__ __launch_bounds__(256) void k_hist2(const int* __restrict__ ei,
                                               uint32* __restrict__ part) {
    __shared__ uint32 h[QN];
    int t = threadIdx.x, b = blockIdx.x;
    int e0 = b * CHUNK, e1 = e0 + CHUNK;
    if (e1 > N_EDGES) e1 = N_EDGES;
    for (int q = 0; q < 4; ++q) {
        int lo = q * QN;
        for (int i = t; i < QN; i += 256) h[i] = 0;
        __syncthreads();
        for (int e = e0 + t; e < e1; e += 256) {
            int s = ei[e], d = ei[N_EDGES + e];
            unsigned rs = (unsigned)(s - lo), rd = (unsigned)(d - lo);
            if (rs < (unsigned)QN) atomicAdd(&h[rs], 1u);
            if (rd < (unsigned)QN) atomicAdd(&h[rd], 0x10000u);
        }
        __syncthreads();
        for (int i = t; i < QN; i += 256) part[b * N_NODES + lo + i] = h[i];
        __syncthreads();
    }
}

// K2: degp[v] = sum_b part[b][v]; block sums of deg_in for the scan.
__global__ __launch_bounds__(256) void k_merge(const uint32* __restrict__ part,
                                               uint32* __restrict__ degp,
                                               int* __restrict__ bsum) {
    int t = threadIdx.x, v = blockIdx.x * 256 + t;
    uint32 s = 0;
    if (v < N_NODES) {
        #pragma unroll 8
        for (int b = 0; b < NB; ++b) s += part[b * N_NODES + v];
        degp[v] = s;
    }
    int din = (int)(s >> 16);
    int r = din;
    #pragma unroll
    for (int d = 1; d < 64; d <<= 1) r += __shfl_xor(r, d);
    __shared__ int wsum[4];
    int lane = t & 63, wid = t >> 6;
    if (lane == 0) wsum[wid] = r;
    __syncthreads();
    if (t == 0) bsum[blockIdx.x] = wsum[0] + wsum[1] + wsum[2] + wsum[3];
}

// K3: exclusive scan of 196 block sums (single block).
__global__ void k_scanb(const int* __restrict__ bsum, int* __restrict__ bbase) {
    int t = threadIdx.x;
    int v = (t < NBLK2) ? bsum[t] : 0;
    int lane = t & 63, wid = t >> 6;
    int x = v;
    #pragma unroll
    for (int d = 1; d < 64; d <<= 1) {
        int y = __shfl_up(x, d);
        if (lane >= d) x += y;
    }
    __shared__ int wsum[4];
    if (lane == 63) wsum[wid] = x;
    __syncthreads();
    int base = 0;
    for (int w = 0; w < wid; ++w) base += wsum[w];
    if (t < NBLK2) bbase[t] = base + x - v;
}

// K4: rowptr[v]; convert part[b][v] in-place into fill offsets
// (rowptr[v] + edges-to-v in chunks < b).
__global__ __launch_bounds__(256) void k_base(uint32* __restrict__ part,
                                              const uint32* __restrict__ degp,
                                              const int* __restrict__ bbase,
                                              int* __restrict__ rowptr) {
    int t = threadIdx.x, v = blockIdx.x * 256 + t;
    int din = (v < N_NODES) ? (int)(degp[v] >> 16) : 0;
    int lane = t & 63, wid = t >> 6;
    int x = din;
    #pragma unroll
    for (int d = 1; d < 64; d <<= 1) {
        int y = __shfl_up(x, d);
        if (lane >= d) x += y;
    }
    __shared__ int wsum[4];
    if (lane == 63) wsum[wid] = x;
    __syncthreads();
    int base = bbase[blockIdx.x];
    for (int w = 0; w < wid; ++w) base += wsum[w];
    int start = base + x - din;
    if (v < N_NODES) {
        rowptr[v] = start;
        if (v == N_NODES - 1) rowptr[N_NODES] = start + din;
        uint32 run = (uint32)start;
        for (int b = 0; b < NB; ++b) {
            uint32 p = part[b * N_NODES + v];
            part[b * N_NODES + v] = run;
            run += (p >> 16);
        }
    }
}

// K5: scatter edges into CSR slots using LDS cursors (no global atomics).
__global__ __launch_bounds__(256) void k_fill2(const int* __restrict__ ei,
                                               const int* __restrict__ etype,
                                               const uint32* __restrict__ fillbase,
                                               int2* __restrict__ csr) {
    __shared__ uint32 cur[QN];
    int t = threadIdx.x, b = blockIdx.x;
    int e0 = b * CHUNK, e1 = e0 + CHUNK;
    if (e1 > N_EDGES) e1 = N_EDGES;
    for (int q = 0; q < 4; ++q) {
        int lo = q * QN;
        for (int i = t; i < QN; i += 256) cur[i] = 0;
        __syncthreads();
        for (int e = e0 + t; e < e1; e += 256) {
            int d = ei[N_EDGES + e];
            unsigned rd = (unsigned)(d - lo);
            if (rd < (unsigned)QN) {
                int s = ei[e], ty = etype[e];
                uint32 c = atomicAdd(&cur[rd], 1u);
                int pos = (int)fillbase[b * N_NODES + d] + (int)c;
                csr[pos] = make_int2(s * 9 + ty, s);
            }
        }
        __syncthreads();
    }
}

// K6: xr[n][r][64] = x[n][:] @ Wall[r]
__global__ __launch_bounds__(256) void k_xr(const float* __restrict__ x,
                                            const float* __restrict__ Wall,
                                            float* __restrict__ xr) {
    __shared__ __align__(16) float At[64 * 68];
    __shared__ __align__(16) float Wt[64 * 64];
    int t = threadIdx.x;
    int n0 = blockIdx.x * 64;
    int r = blockIdx.y;
    #pragma unroll
    for (int j = 0; j < 16; ++j) {
        int f = t + j * 256;
        int n = f >> 6, k = f & 63;
        float v = (n0 + n < N_NODES) ? x[(n0 + n) * 64 + k] : 0.f;
        At[k * 68 + n] = v;
    }
    #pragma unroll
    for (int j = 0; j < 16; ++j) {
        int f = t + j * 256;
        Wt[f] = Wall[r * 4096 + f];
    }
    __syncthreads();
    int cg = t & 15, rg = t >> 4;
    float acc[4][4];
    #pragma unroll
    for (int i = 0; i < 4; ++i)
        #pragma unroll
        for (int j = 0; j < 4; ++j) acc[i][j] = 0.f;
    #pragma unroll 4
    for (int k = 0; k < 64; ++k) {
        float4 a = *(const float4*)&At[k * 68 + 4 * rg];
        float4 w = *(const float4*)&Wt[k * 64 + 4 * cg];
        acc[0][0] += a.x * w.x; acc[0][1] += a.x * w.y; acc[0][2] += a.x * w.z; acc[0][3] += a.x * w.w;
        acc[1][0] += a.y * w.x; acc[1][1] += a.y * w.y; acc[1][2] += a.y * w.z; acc[1][3] += a.y * w.w;
        acc[2][0] += a.z * w.x; acc[2][1] += a.z * w.y; acc[2][2] += a.z * w.z; acc[2][3] += a.z * w.w;
        acc[3][0] += a.w * w.x; acc[3][1] += a.w * w.y; acc[3][2] += a.w * w.z; acc[3][3] += a.w * w.w;
    }
    #pragma unroll
    for (int i = 0; i < 4; ++i) {
        int n = n0 + 4 * rg + i;
        if (n < N_NODES) {
            float4 o = make_float4(acc[i][0], acc[i][1], acc[i][2], acc[i][3]);
            *(float4*)&xr[n * 576 + r * 64 + 4 * cg] = o;
        }
    }
}

// K7: hs[v] = (sum_in xr[csr.x] + xr[v*9+8] + bias1) * rsqrt(deg_out[v])
__global__ __launch_bounds__(256) void k_agg1(const float* __restrict__ xr,
                                              const int2* __restrict__ csr,
                                              const int* __restrict__ rowptr,
                                              const uint32* __restrict__ degp,
                                              const float* __restrict__ bias1,
                                              float* __restrict__ hs) {
    int wid = threadIdx.x >> 6, lane = threadIdx.x & 63;
    int v = blockIdx.x * 4 + wid;
    if (v >= N_NODES) return;
    float acc = xr[(v * 9 + 8) * 64 + lane] + bias1[lane];
    int j = rowptr[v], end = rowptr[v + 1];
    for (; j + 4 <= end; j += 4) {
        int r0 = csr[j].x, r1 = csr[j + 1].x, r2 = csr[j + 2].x, r3 = csr[j + 3].x;
        float a0 = xr[r0 * 64 + lane], a1 = xr[r1 * 64 + lane];
        float a2 = xr[r2 * 64 + lane], a3 = xr[r3 * 64 + lane];
        acc += a0; acc += a1; acc += a2; acc += a3;
    }
    for (; j < end; ++j) acc += xr[csr[j].x * 64 + lane];
    float dg = (float)(degp[v] & 0xffffu);
    if (dg < 1.f) dg = 1.f;
    hs[v * 64 + lane] = acc * rsqrtf(dg);
}

// K8: out[v] = (rsqrt(deg_in[v]) * sum_in hs[csr.y]) @ W2 + bias2
__global__ __launch_bounds__(256) void k_layer2(const float* __restrict__ hs,
                                                const int2* __restrict__ csr,
                                                const int* __restrict__ rowptr,
                                                const uint32* __restrict__ degp,
                                                const float* __restrict__ w2,
                                                const float* __restrict__ bias2,
                                                float* __restrict__ out) {
    __shared__ __align__(16) float W2s[64 * 64];
    __shared__ __align__(16) float ys[4 * 64];
    int t = threadIdx.x;
    #pragma unroll
    for (int j = 0; j < 16; ++j) W2s[t + j * 256] = w2[t + j * 256];
    int wid = t >> 6, lane = t & 63;
    int v = blockIdx.x * 4 + wid;
    float acc = 0.f;
    int j = 0, end = 0;
    if (v < N_NODES) { j = rowptr[v]; end = rowptr[v + 1]; }
    for (; j + 4 <= end; j += 4) {
        int r0 = csr[j].y, r1 = csr[j + 1].y, r2 = csr[j + 2].y, r3 = csr[j + 3].y;
        float a0 = hs[r0 * 64 + lane], a1 = hs[r1 * 64 + lane];
        float a2 = hs[r2 * 64 + lane], a3 = hs[r3 * 64 + lane];
        acc += a0; acc += a1; acc += a2; acc += a3;
    }
    for (; j < end; ++j) acc += hs[csr[j].y * 64 + lane];
    if (v < N_NODES) {
        float dg = (float)(degp[v] >> 16);
        if (dg < 1.f) dg = 1.f;
        ys[wid * 64 + lane] = acc * rsqrtf(dg);
    }
    __syncthreads();
    if (v >= N_NODES) return;
    float o = bias2[lane];
    const float* yrow = &ys[wid * 64];
    #pragma unroll 4
    for (int k = 0; k < 64; ++k) o += yrow[k] * W2s[k * 64 + lane];
    out[v * 64 + lane] = o;
}

extern "C" void kernel_launch(void* const* d_in, const int* in_sizes, int n_in,
                              void* d_out, int out_size, void* d_ws, size_t ws_size,
                              hipStream_t stream) {
    const float* x      = (const float*)d_in[0];
    const int*   ei     = (const int*)d_in[1];   // [2E]: src then dst
    const int*   etype  = (const int*)d_in[3];
    const float* basis  = (const float*)d_in[4];
    const float* comp   = (const float*)d_in[5];
    const float* loopw  = (const float*)d_in[6];
    const float* bias1  = (const float*)d_in[7];
    const float* w2     = (const float*)d_in[8];
    const float* bias2  = (const float*)d_in[9];
    float* out = (float*)d_out;

    char* ws = (char*)d_ws;
    uint32* part   = (uint32*)(ws + A_PART);
    float*  xr     = (float*)(ws + A_XR);      // aliases part; written after fill
    uint32* degp   = (uint32*)(ws + A_DEGP);
    int*    rowptr = (int*)(ws + A_ROWPTR);
    int*    bsum   = (int*)(ws + A_BSUM);
    int*    bbase  = (int*)(ws + A_BBASE);
    int2*   csr    = (int2*)(ws + A_CSR);
    float*  hs     = (float*)(ws + A_HS);
    float*  Wall   = (float*)(ws + A_WALL);

    k_wall<<<144, 256, 0, stream>>>(comp, basis, loopw, Wall);
    k_hist2<<<NB, 256, 0, stream>>>(ei, part);
    k_merge<<<NBLK2, 256, 0, stream>>>(part, degp, bsum);
    k_scanb<<<1, 256, 0, stream>>>(bsum, bbase);
    k_base<<<NBLK2, 256, 0, stream>>>(part, degp, bbase, rowptr);
    k_fill2<<<NB, 256, 0, stream>>>(ei, etype, part, csr);
    k_xr<<<dim3((N_NODES + 63) / 64, 9), 256, 0, stream>>>(x, Wall, xr);
    k_agg1<<<N_NODES / 4, 256, 0, stream>>>(xr, csr, rowptr, degp, bias1, hs);
    k_layer2<<<N_NODES / 4, 256, 0, stream>>>(hs, csr, rowptr, degp, w2, bias2, out);
}

// Round 3
// 317.180 us; speedup vs baseline: 1.4226x; 1.2549x over previous
//
#include <hip/hip_runtime.h>

#define N_NODES 50000
#define N_EDGES 1000000
#define NB      128         // edge chunks
#define CHUNK   7813        // 128*7813 = 1,000,064 >= E
#define NQ      8           // node ranges per chunk (blockIdx.y)
#define QN      6256        // words per range (16B-aligned); 8*6256 = 50048 >= N
#define NBLK2   196         // ceil(50000/256)

// ---- ws layout (bytes) ----
// part[NB][50000] uint (25.6 MB) lives at 0 and is DEAD after k_fill2;
// xr[50000][9][64] float (115.2 MB) reuses offset 0 after the build.
#define A_PART    0
#define A_XR      0
#define A_DEGP    115200000  // uint[50000] packed: deg_in<<16 | deg_out
#define A_ROWPTR  115400000  // int[50001]
#define A_BSUM    115600128  // int[196]
#define A_BBASE   115601024  // int[196]
#define A_CSR     115601920  // int2[1e6]: (src*9+etype, src)
#define A_HS      123601920  // float[50000*64]
#define A_WALL    136401920  // float[9*64*64]  (ends 136,549,376)

typedef unsigned int uint32;

// K0: Wall[r][i][o] = sum_b comp[r][b]*basis[b][i][o]; Wall[8] = loop_weight
__global__ void k_wall(const float* __restrict__ comp, const float* __restrict__ basis,
                       const float* __restrict__ loopw, float* __restrict__ Wall) {
    int idx = blockIdx.x * 256 + threadIdx.x;
    if (idx >= 9 * 4096) return;
    int r = idx >> 12, io = idx & 4095;
    float acc;
    if (r < 8) {
        acc = 0.f;
        #pragma unroll
        for (int b = 0; b < 30; ++b) acc += comp[r * 30 + b] * basis[b * 4096 + io];
    } else {
        acc = loopw[io];
    }
    Wall[idx] = acc;
}

// K1: per-(chunk, node-range) packed histogram via LDS atomics.
// part[b][v] = (in_count<<16) | out_count for chunk b.
__global__ __launch_bounds__(256) void k_hist2(const int* __restrict__ ei,
                                               uint32* __restrict__ part) {
    __shared__ __align__(16) uint32 h[QN];
    int t = threadIdx.x, b = blockIdx.x, q = blockIdx.y;
    int lo = q * QN;
    int nq = N_NODES - lo; if (nq > QN) nq = QN;
    int4* h4 = (int4*)h;
    for (int i = t; i < QN / 4; i += 256) h4[i] = make_int4(0, 0, 0, 0);
    __syncthreads();
    int e0 = b * CHUNK, e1 = e0 + CHUNK;
    if (e1 > N_EDGES) e1 = N_EDGES;
    for (int e = e0 + t; e < e1; e += 256) {
        int s = ei[e], d = ei[N_EDGES + e];
        unsigned rs = (unsigned)(s - lo), rd = (unsigned)(d - lo);
        if (rs < (unsigned)QN) atomicAdd(&h[rs], 1u);
        if (rd < (unsigned)QN) atomicAdd(&h[rd], 0x10000u);
    }
    __syncthreads();
    int4* d4 = (int4*)(part + b * N_NODES + lo);
    const int4* s4 = (const int4*)h;
    for (int i = t; i < nq / 4; i += 256) d4[i] = s4[i];
}

// K2: degp[v] = sum_b part[b][v]; block sums of deg_in for the scan.
__global__ __launch_bounds__(256) void k_merge(const uint32* __restrict__ part,
                                               uint32* __restrict__ degp,
                                               int* __restrict__ bsum) {
    int t = threadIdx.x, v = blockIdx.x * 256 + t;
    uint32 s = 0;
    if (v < N_NODES) {
        #pragma unroll 8
        for (int b = 0; b < NB; ++b) s += part[b * N_NODES + v];
        degp[v] = s;
    }
    int din = (int)(s >> 16);
    int r = din;
    #pragma unroll
    for (int d = 1; d < 64; d <<= 1) r += __shfl_xor(r, d);
    __shared__ int wsum[4];
    int lane = t & 63, wid = t >> 6;
    if (lane == 0) wsum[wid] = r;
    __syncthreads();
    if (t == 0) bsum[blockIdx.x] = wsum[0] + wsum[1] + wsum[2] + wsum[3];
}

// K3: exclusive scan of 196 block sums (single block).
__global__ void k_scanb(const int* __restrict__ bsum, int* __restrict__ bbase) {
    int t = threadIdx.x;
    int v = (t < NBLK2) ? bsum[t] : 0;
    int lane = t & 63, wid = t >> 6;
    int x = v;
    #pragma unroll
    for (int d = 1; d < 64; d <<= 1) {
        int y = __shfl_up(x, d);
        if (lane >= d) x += y;
    }
    __shared__ int wsum[4];
    if (lane == 63) wsum[wid] = x;
    __syncthreads();
    int base = 0;
    for (int w = 0; w < wid; ++w) base += wsum[w];
    if (t < NBLK2) bbase[t] = base + x - v;
}

// K4: rowptr[v]; convert part[b][v] in-place into fill offsets.
__global__ __launch_bounds__(256) void k_base(uint32* __restrict__ part,
                                              const uint32* __restrict__ degp,
                                              const int* __restrict__ bbase,
                                              int* __restrict__ rowptr) {
    int t = threadIdx.x, v = blockIdx.x * 256 + t;
    int din = (v < N_NODES) ? (int)(degp[v] >> 16) : 0;
    int lane = t & 63, wid = t >> 6;
    int x = din;
    #pragma unroll
    for (int d = 1; d < 64; d <<= 1) {
        int y = __shfl_up(x, d);
        if (lane >= d) x += y;
    }
    __shared__ int wsum[4];
    if (lane == 63) wsum[wid] = x;
    __syncthreads();
    int base = bbase[blockIdx.x];
    for (int w = 0; w < wid; ++w) base += wsum[w];
    int start = base + x - din;
    if (v < N_NODES) {
        rowptr[v] = start;
        if (v == N_NODES - 1) rowptr[N_NODES] = start + din;
        uint32 run = (uint32)start;
        for (int b = 0; b < NB; ++b) {
            uint32 p = part[b * N_NODES + v];
            part[b * N_NODES + v] = run;
            run += (p >> 16);
        }
    }
}

// K5: scatter edges into CSR slots; LDS cursors seeded from fillbase.
__global__ __launch_bounds__(256) void k_fill2(const int* __restrict__ ei,
                                               const int* __restrict__ etype,
                                               const uint32* __restrict__ fillbase,
                                               int2* __restrict__ csr) {
    __shared__ __align__(16) uint32 cur[QN];
    int t = threadIdx.x, b = blockIdx.x, q = blockIdx.y;
    int lo = q * QN;
    int nq = N_NODES - lo; if (nq > QN) nq = QN;
    const int4* s4 = (const int4*)(fillbase + b * N_NODES + lo);
    int4* c4 = (int4*)cur;
    for (int i = t; i < nq / 4; i += 256) c4[i] = s4[i];
    __syncthreads();
    int e0 = b * CHUNK, e1 = e0 + CHUNK;
    if (e1 > N_EDGES) e1 = N_EDGES;
    for (int e = e0 + t; e < e1; e += 256) {
        int d = ei[N_EDGES + e];
        unsigned rd = (unsigned)(d - lo);
        if (rd < (unsigned)QN) {
            int s = ei[e], ty = etype[e];
            uint32 pos = atomicAdd(&cur[rd], 1u);
            csr[pos] = make_int2(s * 9 + ty, s);
        }
    }
}

// K6: xr[n][r][64] = x[n][:] @ Wall[r]
__global__ __launch_bounds__(256) void k_xr(const float* __restrict__ x,
                                            const float* __restrict__ Wall,
                                            float* __restrict__ xr) {
    __shared__ __align__(16) float At[64 * 68];
    __shared__ __align__(16) float Wt[64 * 64];
    int t = threadIdx.x;
    int n0 = blockIdx.x * 64;
    int r = blockIdx.y;
    #pragma unroll
    for (int j = 0; j < 16; ++j) {
        int f = t + j * 256;
        int n = f >> 6, k = f & 63;
        float v = (n0 + n < N_NODES) ? x[(n0 + n) * 64 + k] : 0.f;
        At[k * 68 + n] = v;
    }
    #pragma unroll
    for (int j = 0; j < 16; ++j) {
        int f = t + j * 256;
        Wt[f] = Wall[r * 4096 + f];
    }
    __syncthreads();
    int cg = t & 15, rg = t >> 4;
    float acc[4][4];
    #pragma unroll
    for (int i = 0; i < 4; ++i)
        #pragma unroll
        for (int j = 0; j < 4; ++j) acc[i][j] = 0.f;
    #pragma unroll 4
    for (int k = 0; k < 64; ++k) {
        float4 a = *(const float4*)&At[k * 68 + 4 * rg];
        float4 w = *(const float4*)&Wt[k * 64 + 4 * cg];
        acc[0][0] += a.x * w.x; acc[0][1] += a.x * w.y; acc[0][2] += a.x * w.z; acc[0][3] += a.x * w.w;
        acc[1][0] += a.y * w.x; acc[1][1] += a.y * w.y; acc[1][2] += a.y * w.z; acc[1][3] += a.y * w.w;
        acc[2][0] += a.z * w.x; acc[2][1] += a.z * w.y; acc[2][2] += a.z * w.z; acc[2][3] += a.z * w.w;
        acc[3][0] += a.w * w.x; acc[3][1] += a.w * w.y; acc[3][2] += a.w * w.z; acc[3][3] += a.w * w.w;
    }
    #pragma unroll
    for (int i = 0; i < 4; ++i) {
        int n = n0 + 4 * rg + i;
        if (n < N_NODES) {
            float4 o = make_float4(acc[i][0], acc[i][1], acc[i][2], acc[i][3]);
            *(float4*)&xr[n * 576 + r * 64 + 4 * cg] = o;
        }
    }
}

// K7: hs[v] = (sum_in xr[csr.x] + xr[v*9+8] + bias1) * rsqrt(deg_out[v])
__global__ __launch_bounds__(256) void k_agg1(const float* __restrict__ xr,
                                              const int2* __restrict__ csr,
                                              const int* __restrict__ rowptr,
                                              const uint32* __restrict__ degp,
                                              const float* __restrict__ bias1,
                                              float* __restrict__ hs) {
    int wid = threadIdx.x >> 6, lane = threadIdx.x & 63;
    int v = blockIdx.x * 4 + wid;
    if (v >= N_NODES) return;
    float acc = xr[(v * 9 + 8) * 64 + lane] + bias1[lane];
    int j = rowptr[v], end = rowptr[v + 1];
    for (; j + 4 <= end; j += 4) {
        int r0 = csr[j].x, r1 = csr[j + 1].x, r2 = csr[j + 2].x, r3 = csr[j + 3].x;
        float a0 = xr[r0 * 64 + lane], a1 = xr[r1 * 64 + lane];
        float a2 = xr[r2 * 64 + lane], a3 = xr[r3 * 64 + lane];
        acc += a0; acc += a1; acc += a2; acc += a3;
    }
    for (; j < end; ++j) acc += xr[csr[j].x * 64 + lane];
    float dg = (float)(degp[v] & 0xffffu);
    if (dg < 1.f) dg = 1.f;
    hs[v * 64 + lane] = acc * rsqrtf(dg);
}

// K8: out[v] = (rsqrt(deg_in[v]) * sum_in hs[csr.y]) @ W2 + bias2
__global__ __launch_bounds__(256) void k_layer2(const float* __restrict__ hs,
                                                const int2* __restrict__ csr,
                                                const int* __restrict__ rowptr,
                                                const uint32* __restrict__ degp,
                                                const float* __restrict__ w2,
                                                const float* __restrict__ bias2,
                                                float* __restrict__ out) {
    __shared__ __align__(16) float W2s[64 * 64];
    __shared__ __align__(16) float ys[4 * 64];
    int t = threadIdx.x;
    #pragma unroll
    for (int j = 0; j < 16; ++j) W2s[t + j * 256] = w2[t + j * 256];
    int wid = t >> 6, lane = t & 63;
    int v = blockIdx.x * 4 + wid;
    float acc = 0.f;
    int j = 0, end = 0;
    if (v < N_NODES) { j = rowptr[v]; end = rowptr[v + 1]; }
    for (; j + 4 <= end; j += 4) {
        int r0 = csr[j].y, r1 = csr[j + 1].y, r2 = csr[j + 2].y, r3 = csr[j + 3].y;
        float a0 = hs[r0 * 64 + lane], a1 = hs[r1 * 64 + lane];
        float a2 = hs[r2 * 64 + lane], a3 = hs[r3 * 64 + lane];
        acc += a0; acc += a1; acc += a2; acc += a3;
    }
    for (; j < end; ++j) acc += hs[csr[j].y * 64 + lane];
    if (v < N_NODES) {
        float dg = (float)(degp[v] >> 16);
        if (dg < 1.f) dg = 1.f;
        ys[wid * 64 + lane] = acc * rsqrtf(dg);
    }
    __syncthreads();
    if (v >= N_NODES) return;
    float o = bias2[lane];
    const float* yrow = &ys[wid * 64];
    #pragma unroll 4
    for (int k = 0; k < 64; ++k) o += yrow[k] * W2s[k * 64 + lane];
    out[v * 64 + lane] = o;
}

extern "C" void kernel_launch(void* const* d_in, const int* in_sizes, int n_in,
                              void* d_out, int out_size, void* d_ws, size_t ws_size,
                              hipStream_t stream) {
    const float* x      = (const float*)d_in[0];
    const int*   ei     = (const int*)d_in[1];   // [2E]: src then dst
    const int*   etype  = (const int*)d_in[3];
    const float* basis  = (const float*)d_in[4];
    const float* comp   = (const float*)d_in[5];
    const float* loopw  = (const float*)d_in[6];
    const float* bias1  = (const float*)d_in[7];
    const float* w2     = (const float*)d_in[8];
    const float* bias2  = (const float*)d_in[9];
    float* out = (float*)d_out;

    char* ws = (char*)d_ws;
    uint32* part   = (uint32*)(ws + A_PART);
    float*  xr     = (float*)(ws + A_XR);      // aliases part; written after fill
    uint32* degp   = (uint32*)(ws + A_DEGP);
    int*    rowptr = (int*)(ws + A_ROWPTR);
    int*    bsum   = (int*)(ws + A_BSUM);
    int*    bbase  = (int*)(ws + A_BBASE);
    int2*   csr    = (int2*)(ws + A_CSR);
    float*  hs     = (float*)(ws + A_HS);
    float*  Wall   = (float*)(ws + A_WALL);

    k_wall<<<144, 256, 0, stream>>>(comp, basis, loopw, Wall);
    k_hist2<<<dim3(NB, NQ), 256, 0, stream>>>(ei, part);
    k_merge<<<NBLK2, 256, 0, stream>>>(part, degp, bsum);
    k_scanb<<<1, 256, 0, stream>>>(bsum, bbase);
    k_base<<<NBLK2, 256, 0, stream>>>(part, degp, bbase, rowptr);
    k_fill2<<<dim3(NB, NQ), 256, 0, stream>>>(ei, etype, part, csr);
    k_xr<<<dim3((N_NODES + 63) / 64, 9), 256, 0, stream>>>(x, Wall, xr);
    k_agg1<<<N_NODES / 4, 256, 0, stream>>>(xr, csr, rowptr, degp, bias1, hs);
    k_layer2<<<N_NODES / 4, 256, 0, stream>>>(hs, csr, rowptr, degp, w2, bias2, out);
}